// Round 13
// baseline (224.145 us; speedup 1.0000x reference)
//
#include <hip/hip_runtime.h>
#include <hip/hip_bf16.h>

// ---------------------------------------------------------------------------
// GIN (3 layers, eps=0) + global mean pool + FC.
//
// Lessons: r1 global f32 atomics = 64B write-through; r2 per-node CSR fill =
//   105MB dirty lines; r3 block-per-bucket agg = latency collapse; r5 linears
//   LDS-read-bound -> r6 MFMA linears; r7 __shfl in divergent flow = garbage;
//   r8 1 node/wave = serial-chain bound; r9 4 nodes/wave + 8 loads in flight
//   = sweet spot (43us, VGPR 48); r10 global atomics on hot bins = RMW
//   serialization; r11 degree-balancing = zero gain (gather at random-row
//   throughput); r12 16-deep unroll = VGPR 60/occ 35% regression AND
//   per-block LDS W-staging ate the fusion win.
// r13: gather reverted to 8-deep; linear23 v2: W2/W3 pre-converted to bf16
//   once (wprep), B-frags read straight from global (32KB, L1-resident),
//   LDS = H2 tile only (17.4KB), zero barriers.
// ---------------------------------------------------------------------------

#define NBLK 256      // blocks for edge count/fill
#define CFBS 512      // threads for edge count/fill
#define RB   128      // nodes per bucket
#define NBMAX 1024    // max buckets (N <= 131072)
#define SCBS 1024     // scan chunk

__device__ inline float bf2f(unsigned short u) {
    return __uint_as_float((unsigned)u << 16);
}
__device__ inline unsigned short f2bf(float f) {
    unsigned x = __float_as_uint(f);
    return (unsigned short)((x + 0x7FFFu + ((x >> 16) & 1u)) >> 16);  // RNE
}
__device__ inline float lo16(unsigned u) { return __uint_as_float(u << 16); }
__device__ inline float hi16(unsigned u) { return __uint_as_float(u & 0xFFFF0000u); }

// ---- bucket build ---------------------------------------------------------

__global__ __launch_bounds__(CFBS) void count_kernel(
    const int* __restrict__ dst, int* __restrict__ cnt, int E, int NB)
{
    __shared__ int hist[NBMAX];
    int tid = threadIdx.x;
    for (int i = tid; i < NBMAX; i += CFBS) hist[i] = 0;
    __syncthreads();
    for (int e = blockIdx.x * CFBS + tid; e < E; e += NBLK * CFBS)
        atomicAdd(&hist[dst[e] >> 7], 1);
    __syncthreads();
    for (int b = tid; b < NB; b += CFBS)
        cnt[b * NBLK + blockIdx.x] = hist[b];
}

__global__ __launch_bounds__(SCBS) void scan_k1(
    const int* __restrict__ cnt, int* __restrict__ ofs,
    int* __restrict__ part, int NT)
{
    __shared__ int tmp[SCBS];
    int i = blockIdx.x * SCBS + threadIdx.x;
    int v = (i < NT) ? cnt[i] : 0;
    tmp[threadIdx.x] = v;
    __syncthreads();
    for (int off = 1; off < SCBS; off <<= 1) {
        int t = (threadIdx.x >= off) ? tmp[threadIdx.x - off] : 0;
        __syncthreads();
        tmp[threadIdx.x] += t;
        __syncthreads();
    }
    if (i < NT) ofs[i] = tmp[threadIdx.x] - v;   // exclusive within chunk
    if (threadIdx.x == SCBS - 1) part[blockIdx.x] = tmp[threadIdx.x];
}

__global__ __launch_bounds__(SCBS) void scan_k2(int* __restrict__ part, int B)
{
    __shared__ int tmp[SCBS];
    int v = (threadIdx.x < B) ? part[threadIdx.x] : 0;
    tmp[threadIdx.x] = v;
    __syncthreads();
    for (int off = 1; off < SCBS; off <<= 1) {
        int t = (threadIdx.x >= off) ? tmp[threadIdx.x - off] : 0;
        __syncthreads();
        tmp[threadIdx.x] += t;
        __syncthreads();
    }
    if (threadIdx.x < B) part[threadIdx.x] = tmp[threadIdx.x] - v;
}

__global__ __launch_bounds__(SCBS) void scan_k3(
    int* __restrict__ ofs, const int* __restrict__ part, int NT)
{
    int i = blockIdx.x * SCBS + threadIdx.x;
    if (i < NT) ofs[i] += part[blockIdx.x];
}

__global__ __launch_bounds__(CFBS) void fillp_kernel(
    const int* __restrict__ src, const int* __restrict__ dst,
    const int* __restrict__ ofs, int* __restrict__ pairs, int E, int NB)
{
    __shared__ int cur[NBMAX];
    int tid = threadIdx.x;
    for (int b = tid; b < NB; b += CFBS)
        cur[b] = ofs[b * NBLK + blockIdx.x];
    __syncthreads();
    for (int e = blockIdx.x * CFBS + tid; e < E; e += NBLK * CFBS) {
        int d = dst[e];
        int b = d >> 7, dl = d & 127;
        int pos = atomicAdd(&cur[b], 1);
        pairs[pos] = (dl << 20) | src[e];
    }
}

// per-bucket CSR finalize: writes land in bucket-local contiguous windows
__global__ __launch_bounds__(512) void bucket_csr_kernel(
    const int* __restrict__ pairs, const int* __restrict__ ofs,
    int* __restrict__ rowstart, int* __restrict__ eidx, int N, int E, int NB)
{
    __shared__ int deg[RB], pfx[RB], cur[RB];
    int tid = threadIdx.x;
    int b = blockIdx.x, n0 = b << 7;
    int e0 = ofs[b * NBLK];
    int e1 = (b + 1 < NB) ? ofs[(b + 1) * NBLK] : E;
    if (tid < RB) deg[tid] = 0;
    __syncthreads();
    for (int e = e0 + tid; e < e1; e += 512)
        atomicAdd(&deg[pairs[e] >> 20], 1);
    __syncthreads();
    if (tid < RB) pfx[tid] = deg[tid];
    __syncthreads();
    for (int off = 1; off < RB; off <<= 1) {
        int t = (tid < RB && tid >= off) ? pfx[tid - off] : 0;
        __syncthreads();
        if (tid < RB) pfx[tid] += t;
        __syncthreads();
    }
    if (tid < RB) {
        int ex = pfx[tid] - deg[tid];     // exclusive
        cur[tid] = ex;
        int n = n0 + tid;
        if (n < N) rowstart[n] = e0 + ex;
    }
    if (b == NB - 1 && tid == 0) rowstart[N] = E;
    __syncthreads();
    for (int e = e0 + tid; e < e1; e += 512) {
        int p = pairs[e];
        int pos = e0 + atomicAdd(&cur[p >> 20], 1);
        eidx[pos] = p & 0xFFFFF;
    }
}

// ---- prep: xb[N][16] bf16 (pad 9->16); W2/W3 -> bf16 once ----------------

__global__ __launch_bounds__(256) void xprep_kernel(
    const float* __restrict__ x, unsigned short* __restrict__ xb, int N)
{
    int n = blockIdx.x * 256 + threadIdx.x;
    if (n >= N) return;
    unsigned short r[16];
    #pragma unroll
    for (int k = 0; k < 9; ++k) r[k] = f2bf(x[(size_t)n * 9 + k]);
    #pragma unroll
    for (int k = 9; k < 16; ++k) r[k] = 0;
    uint4 u0, u1;
    u0.x = r[0] | ((unsigned)r[1] << 16);  u0.y = r[2] | ((unsigned)r[3] << 16);
    u0.z = r[4] | ((unsigned)r[5] << 16);  u0.w = r[6] | ((unsigned)r[7] << 16);
    u1.x = r[8] | ((unsigned)r[9] << 16);  u1.y = 0; u1.z = 0; u1.w = 0;
    *(uint4*)&xb[(size_t)n * 16]     = u0;
    *(uint4*)&xb[(size_t)n * 16 + 8] = u1;
}

__global__ __launch_bounds__(256) void wprep_kernel(
    const float* __restrict__ W2, const float* __restrict__ W3,
    unsigned short* __restrict__ w2b, unsigned short* __restrict__ w3b)
{
    int i = blockIdx.x * 256 + threadIdx.x;
    if (i < 128 * 64) w2b[i] = f2bf(W2[i]);
    if (i < 64 * 128) w3b[i] = f2bf(W3[i]);
}

// ---- layer 1: 9-dim gather + Lin 9->64 + relu, 4 nodes per wave ----------

__global__ __launch_bounds__(256) void node1v_kernel(
    const unsigned short* __restrict__ xb, const int* __restrict__ rs,
    const int* __restrict__ eidx, const float* __restrict__ W1,
    const float* __restrict__ b1, unsigned short* __restrict__ h1, int N)
{
    __shared__ float Wl[576];
    __shared__ float bl[64];
    for (int i = threadIdx.x; i < 576; i += 256) Wl[i] = W1[i];
    if (threadIdx.x < 64) bl[threadIdx.x] = b1[threadIdx.x];
    __syncthreads();
    int wid = threadIdx.x >> 6;
    int lane = threadIdx.x & 63;
    int g  = lane >> 2;     // edge group 0..15
    int d4 = lane & 3;      // dims 4*d4 .. 4*d4+3
    int nb = blockIdx.x * 16 + wid * 4;   // this wave's 4 nodes
    if (nb >= N) return;

    int n[4], e0[4], dg[4];
    float A0[4], A1[4], A2[4], A3[4];
    #pragma unroll
    for (int i = 0; i < 4; ++i) {
        n[i] = min(nb + i, N - 1);
        e0[i] = rs[n[i]];
        dg[i] = rs[n[i] + 1] - e0[i];
        A0[i] = A1[i] = A2[i] = A3[i] = 0.f;
    }
    #pragma unroll
    for (int i = 0; i < 4; ++i) {
        if (g == 0) {       // self term
            uint2 u = *(const uint2*)&xb[(size_t)n[i] * 16 + d4 * 4];
            A0[i] += lo16(u.x); A1[i] += hi16(u.x);
            A2[i] += lo16(u.y); A3[i] += hi16(u.y);
        }
    }
    int mdeg = max(max(dg[0], dg[1]), max(dg[2], dg[3]));
    for (int w0 = 0; w0 < mdeg; w0 += 64) {
        int sidx[4], wd[4];
        #pragma unroll
        for (int i = 0; i < 4; ++i) {
            wd[i] = min(max(dg[i] - w0, 0), 64);
            sidx[i] = (lane < wd[i]) ? eidx[e0[i] + w0 + lane] : 0;
        }
        int mwd = max(max(wd[0], wd[1]), max(wd[2], wd[3]));
        for (int c = 0; c < mwd; c += 16) {
            #pragma unroll
            for (int i = 0; i < 4; ++i) {
                int idx = c + g;
                int s = __shfl(sidx[i], idx < wd[i] ? idx : 0); // uniform flow
                float m = (idx < wd[i]) ? 1.f : 0.f;
                uint2 u = *(const uint2*)&xb[(size_t)s * 16 + d4 * 4];
                A0[i] += m * lo16(u.x); A1[i] += m * hi16(u.x);
                A2[i] += m * lo16(u.y); A3[i] += m * hi16(u.y);
            }
        }
    }
    #pragma unroll
    for (int m = 4; m < 64; m <<= 1) {
        #pragma unroll
        for (int i = 0; i < 4; ++i) {
            A0[i] += __shfl_xor(A0[i], m); A1[i] += __shfl_xor(A1[i], m);
            A2[i] += __shfl_xor(A2[i], m); A3[i] += __shfl_xor(A3[i], m);
        }
    }
    const float* wr = &Wl[lane * 9];
    #pragma unroll
    for (int i = 0; i < 4; ++i) {
        float xv0 = __shfl(A0[i], 0), xv1 = __shfl(A1[i], 0);
        float xv2 = __shfl(A2[i], 0), xv3 = __shfl(A3[i], 0);
        float xv4 = __shfl(A0[i], 1), xv5 = __shfl(A1[i], 1);
        float xv6 = __shfl(A2[i], 1), xv7 = __shfl(A3[i], 1);
        float xv8 = __shfl(A0[i], 2);
        float s = bl[lane] + xv0 * wr[0] + xv1 * wr[1] + xv2 * wr[2]
                + xv3 * wr[3] + xv4 * wr[4] + xv5 * wr[5] + xv6 * wr[6]
                + xv7 * wr[7] + xv8 * wr[8];
        if (nb + i < N)
            h1[(size_t)(nb + i) * 64 + lane] = f2bf(fmaxf(s, 0.f));
    }
}

// ---- 64-dim gather, 4 nodes/wave, 8 edges per inner iter (r9/r11 form) ---

template<bool BIAS_RELU>
__global__ __launch_bounds__(256) void gather64v_kernel(
    const unsigned short* __restrict__ feat, const int* __restrict__ rs,
    const int* __restrict__ eidx, const float* __restrict__ bias,
    unsigned short* __restrict__ out, int N)
{
    int wid = threadIdx.x >> 6;
    int lane = threadIdx.x & 63;
    int g  = lane >> 4;     // edge group 0..3
    int d4 = lane & 15;     // dims 4*d4 .. 4*d4+3
    int nb = blockIdx.x * 16 + wid * 4;
    if (nb >= N) return;

    int n[4], e0[4], dg[4];
    float A0[4], A1[4], A2[4], A3[4];
    #pragma unroll
    for (int i = 0; i < 4; ++i) {
        n[i] = min(nb + i, N - 1);
        e0[i] = rs[n[i]];
        dg[i] = rs[n[i] + 1] - e0[i];
        A0[i] = A1[i] = A2[i] = A3[i] = 0.f;
    }
    #pragma unroll
    for (int i = 0; i < 4; ++i) {
        if (g == 0) {       // self term
            uint2 u = *(const uint2*)&feat[(size_t)n[i] * 64 + d4 * 4];
            A0[i] += lo16(u.x); A1[i] += hi16(u.x);
            A2[i] += lo16(u.y); A3[i] += hi16(u.y);
        }
    }
    int mdeg = max(max(dg[0], dg[1]), max(dg[2], dg[3]));
    for (int w0 = 0; w0 < mdeg; w0 += 64) {
        int sidx[4], wd[4];
        #pragma unroll
        for (int i = 0; i < 4; ++i) {
            wd[i] = min(max(dg[i] - w0, 0), 64);
            sidx[i] = (lane < wd[i]) ? eidx[e0[i] + w0 + lane] : 0;
        }
        int mwd = max(max(wd[0], wd[1]), max(wd[2], wd[3]));
        for (int c = 0; c < mwd; c += 8) {
            #pragma unroll
            for (int i = 0; i < 4; ++i) {   // 8 independent loads in flight
                int i0 = c + g, i1 = c + 4 + g;
                int s0 = __shfl(sidx[i], i0 < wd[i] ? i0 : 0);  // uniform flow
                int s1 = __shfl(sidx[i], i1 < wd[i] ? i1 : 0);
                float m0 = (i0 < wd[i]) ? 1.f : 0.f;
                float m1 = (i1 < wd[i]) ? 1.f : 0.f;
                uint2 u0 = *(const uint2*)&feat[(size_t)s0 * 64 + d4 * 4];
                uint2 u1 = *(const uint2*)&feat[(size_t)s1 * 64 + d4 * 4];
                A0[i] += m0 * lo16(u0.x) + m1 * lo16(u1.x);
                A1[i] += m0 * hi16(u0.x) + m1 * hi16(u1.x);
                A2[i] += m0 * lo16(u0.y) + m1 * lo16(u1.y);
                A3[i] += m0 * hi16(u0.y) + m1 * hi16(u1.y);
            }
        }
    }
    #pragma unroll
    for (int m = 16; m < 64; m <<= 1) {
        #pragma unroll
        for (int i = 0; i < 4; ++i) {
            A0[i] += __shfl_xor(A0[i], m); A1[i] += __shfl_xor(A1[i], m);
            A2[i] += __shfl_xor(A2[i], m); A3[i] += __shfl_xor(A3[i], m);
        }
    }
    float4 bv = make_float4(0.f, 0.f, 0.f, 0.f);
    if (BIAS_RELU) bv = *(const float4*)&bias[d4 * 4];
    #pragma unroll
    for (int i = 0; i < 4; ++i) {
        if (g == 0 && nb + i < N) {
            float a0 = A0[i], a1 = A1[i], a2 = A2[i], a3 = A3[i];
            if (BIAS_RELU) {
                a0 = fmaxf(a0 + bv.x, 0.f); a1 = fmaxf(a1 + bv.y, 0.f);
                a2 = fmaxf(a2 + bv.z, 0.f); a3 = fmaxf(a3 + bv.w, 0.f);
            }
            ushort4 u;
            u.x = f2bf(a0); u.y = f2bf(a1); u.z = f2bf(a2); u.w = f2bf(a3);
            *(ushort4*)&out[(size_t)(nb + i) * 64 + d4 * 4] = u;
        }
    }
}

// ---- fused linear2+linear3: t3 = W3 . relu(W2 . a + b2) -------------------
// v2: B-frags straight from global bf16 (w2b 16KB + w3b 16KB = L1-resident);
// LDS = H2 tile only (64x136 ushort, wave-private strips, zero barriers).
//   A-frag 16x16x32: lane l -> row l&15, k-slice (l>>4)*8
//   C/D:             col = lane&15, row = (lane>>4)*4 + reg  [m89-verified]

__global__ __launch_bounds__(256) void linear23_fused_kernel(
    const unsigned short* __restrict__ A, const unsigned short* __restrict__ w2b,
    const float* __restrict__ b2, const unsigned short* __restrict__ w3b,
    unsigned short* __restrict__ t3, int N)
{
    using s8v = __attribute__((ext_vector_type(8))) short;
    using f4v = __attribute__((ext_vector_type(4))) float;
    __shared__ __align__(16) unsigned short H2[64 * 136];    // h2 tile [node][128]
    int tid = threadIdx.x;
    int w = tid >> 6, lane = tid & 63;
    int n0 = blockIdx.x * 64 + w * 16;
    int hl = lane >> 4;               // k-slice 0..3
    int ll = lane & 15;               // row (A) / col (B)

    // ---- stage 1: h2 = relu(A @ W2^T + b2) -> LDS strip ----
    int an = min(n0 + ll, N - 1);     // clamp: junk rows stay in LDS only
    const unsigned short* arow = &A[(size_t)an * 64 + hl * 8];
    s8v a1[2];
    a1[0] = *(const s8v*)&arow[0];
    a1[1] = *(const s8v*)&arow[32];

    #pragma unroll
    for (int c = 0; c < 8; ++c) {
        f4v acc = (f4v){0.f, 0.f, 0.f, 0.f};
        const unsigned short* wrow = &w2b[(c * 16 + ll) * 64 + hl * 8];
        acc = __builtin_amdgcn_mfma_f32_16x16x32_bf16(a1[0], *(const s8v*)&wrow[0],  acc, 0, 0, 0);
        acc = __builtin_amdgcn_mfma_f32_16x16x32_bf16(a1[1], *(const s8v*)&wrow[32], acc, 0, 0, 0);
        int col = c * 16 + ll;
        float bv = b2[col];
        #pragma unroll
        for (int r = 0; r < 4; ++r) {
            int nrow = w * 16 + hl * 4 + r;          // block-local node row
            H2[nrow * 136 + col] = f2bf(fmaxf(acc[r] + bv, 0.f));
        }
    }
    // wave-private strip: same wave wrote rows w*16..w*16+15 it now reads;
    // compiler inserts lgkmcnt waits. No cross-wave sharing -> no barrier.

    // ---- stage 2: t3 = h2 @ W3^T ----
    const unsigned short* hrow = &H2[(w * 16 + ll) * 136 + hl * 8];
    s8v a2[4];
    #pragma unroll
    for (int ks = 0; ks < 4; ++ks) a2[ks] = *(const s8v*)&hrow[ks * 32];

    #pragma unroll
    for (int c = 0; c < 4; ++c) {
        f4v acc = (f4v){0.f, 0.f, 0.f, 0.f};
        const unsigned short* wrow = &w3b[(c * 16 + ll) * 128 + hl * 8];
        #pragma unroll
        for (int ks = 0; ks < 4; ++ks)
            acc = __builtin_amdgcn_mfma_f32_16x16x32_bf16(a2[ks], *(const s8v*)&wrow[ks * 32], acc, 0, 0, 0);
        int col = c * 16 + ll;
        #pragma unroll
        for (int r = 0; r < 4; ++r) {
            int gn = n0 + hl * 4 + r;
            if (gn < N)
                t3[(size_t)gn * 64 + col] = f2bf(acc[r]);
        }
    }
}

// ---- pool + FC ------------------------------------------------------------

__device__ inline int lower_bound_i(const int* a, int n, int v) {
    int lo = 0, hi = n;
    while (lo < hi) {
        int mid = (lo + hi) >> 1;
        if (a[mid] < v) lo = mid + 1; else hi = mid;
    }
    return lo;
}

__global__ __launch_bounds__(256) void pool_fc_kernel(
    const unsigned short* __restrict__ h3, const int* __restrict__ batch,
    const float* __restrict__ Wfc, const float* __restrict__ bfc,
    float* __restrict__ out, int N)
{
    int g = blockIdx.x;
    int tid = threadIdx.x;
    int w = tid >> 6, lane = tid & 63;
    int lo = lower_bound_i(batch, N, g);
    int hi = lower_bound_i(batch, N, g + 1);
    float sum = 0.f;
    for (int i = lo + w; i < hi; i += 4)
        sum += bf2f(h3[(size_t)i * 64 + lane]);
    __shared__ float P[4][64];
    P[w][lane] = sum;
    __syncthreads();
    if (w == 0) {
        float s = P[0][lane] + P[1][lane] + P[2][lane] + P[3][lane];
        float cnt = (float)((hi - lo) > 0 ? (hi - lo) : 1);
        P[0][lane] = s / cnt;
    }
    __syncthreads();
    if (tid < 11) {
        float s = bfc[tid];
        const float* wr = &Wfc[tid * 64];
        #pragma unroll 8
        for (int k = 0; k < 64; ++k) s += P[0][k] * wr[k];
        out[g * 11 + tid] = s;
    }
}

// ---------------------------------------------------------------------------

extern "C" void kernel_launch(void* const* d_in, const int* in_sizes, int n_in,
                              void* d_out, int out_size, void* d_ws, size_t ws_size,
                              hipStream_t stream) {
    const float* x    = (const float*)d_in[0];
    const int*   ei   = (const int*)d_in[1];
    const int*   batch= (const int*)d_in[2];
    const float* W1   = (const float*)d_in[3];
    const float* b1   = (const float*)d_in[4];
    const float* W2   = (const float*)d_in[5];
    const float* b2   = (const float*)d_in[6];
    const float* W3   = (const float*)d_in[7];
    const float* b3   = (const float*)d_in[8];
    const float* Wfc  = (const float*)d_in[9];
    const float* bfc  = (const float*)d_in[10];
    float* out = (float*)d_out;

    const int N = in_sizes[2];
    const int E = in_sizes[1] / 2;
    const int G = out_size / 11;
    const int* src = ei;
    const int* dst = ei + E;
    const int NB = (N + RB - 1) / RB;      // buckets
    const int NT = NB * NBLK;              // count entries
    const int SB = (NT + SCBS - 1) / SCBS; // scan chunks

    // workspace (bf16 tables):
    //   B1 64N (h1 -> t3) | B2 64N (buf2 -> h3) | XB 16N (xb)
    //   ints: pairs E | eidx E | rowstart N+1 | cnt NT | ofs NT | part SCBS
    //   then w2b/w3b (bf16 weights, 16B-aligned)
    unsigned short* B1 = (unsigned short*)d_ws;
    unsigned short* B2 = B1 + (size_t)64 * N;
    unsigned short* XB = B2 + (size_t)64 * N;
    int* pairs    = (int*)(XB + (size_t)16 * N);
    int* eidx     = pairs + E;
    int* rowstart = eidx + E;
    int* cnt      = rowstart + (N + 1);
    int* ofs      = cnt + NT;
    int* part     = ofs + NT;
    unsigned short* w2b =
        (unsigned short*)(((uintptr_t)(part + SCBS) + 15) & ~(uintptr_t)15);
    unsigned short* w3b = w2b + 128 * 64;

    unsigned short* h1   = B1;
    unsigned short* buf2 = B2;
    unsigned short* t3   = B1;   // h1 dead after gather2
    unsigned short* h3   = B2;   // buf2 dead after fused linear
    unsigned short* xb   = XB;

    // ---- build: bucket-grouped pairs, then per-bucket CSR ----
    count_kernel<<<NBLK, CFBS, 0, stream>>>(dst, cnt, E, NB);
    scan_k1<<<SB, SCBS, 0, stream>>>(cnt, ofs, part, NT);
    scan_k2<<<1, SCBS, 0, stream>>>(part, SB);
    scan_k3<<<SB, SCBS, 0, stream>>>(ofs, part, NT);
    fillp_kernel<<<NBLK, CFBS, 0, stream>>>(src, dst, ofs, pairs, E, NB);
    bucket_csr_kernel<<<NB, 512, 0, stream>>>(pairs, ofs, rowstart, eidx, N, E, NB);
    xprep_kernel<<<(N + 255) / 256, 256, 0, stream>>>(x, xb, N);
    wprep_kernel<<<32, 256, 0, stream>>>(W2, W3, w2b, w3b);

    // ---- layer 1: vectorized 9-dim gather + Lin 9->64 + relu ----
    node1v_kernel<<<(N + 15) / 16, 256, 0, stream>>>(
        xb, rowstart, eidx, W1, b1, h1, N);

    // ---- layer 2 gather, then fused Lin2+Lin3 (h2 never leaves LDS) ----
    gather64v_kernel<false><<<(N + 15) / 16, 256, 0, stream>>>(
        h1, rowstart, eidx, nullptr, buf2, N);
    linear23_fused_kernel<<<(N + 63) / 64, 256, 0, stream>>>(
        buf2, w2b, b2, w3b, t3, N);

    // ---- layer 3 gather (+b3, relu) ----
    gather64v_kernel<true><<<(N + 15) / 16, 256, 0, stream>>>(
        t3, rowstart, eidx, b3, h3, N);

    // ---- pool + FC ----
    pool_fc_kernel<<<G, 256, 0, stream>>>(h3, batch, Wfc, bfc, out, N);
}

// Round 14
// 203.457 us; speedup vs baseline: 1.1017x; 1.1017x over previous
//
#include <hip/hip_runtime.h>
#include <hip/hip_bf16.h>

// ---------------------------------------------------------------------------
// GIN (3 layers, eps=0) + global mean pool + FC.
//
// Lessons: r1 global f32 atomics = 64B write-through; r2 per-node CSR fill =
//   105MB dirty lines; r3 block-per-bucket agg = latency collapse; r5 linears
//   LDS-read-bound -> r6 MFMA linears; r7 __shfl in divergent flow = garbage;
//   r8 1 node/wave = serial-chain bound; r9 4 nodes/wave + 8 loads in flight
//   = gather sweet spot (43us, VGPR 48); r10 global atomics on hot bins =
//   RMW serialization; r11 degree-balancing = zero gain (gather at random-row
//   L3 throughput ~2.3TB/s); r12 16-deep unroll = VGPR/occ regression, and
//   scalar-f2bf LDS W-staging ate the fusion win; r13 B-frags-from-global =
//   +12us (32 serial L1 loads/wave, ~4 blocks/CU can't hide them).
// r14: linear23 v3 = LDS staging (v1) of PRE-CONVERTED bf16 weights (r13's
//   wprep) via vectorized uint4 copies; xprep+wprep merged into one prep.
// ---------------------------------------------------------------------------

#define NBLK 256      // blocks for edge count/fill
#define CFBS 512      // threads for edge count/fill
#define RB   128      // nodes per bucket
#define NBMAX 1024    // max buckets (N <= 131072)
#define SCBS 1024     // scan chunk

__device__ inline float bf2f(unsigned short u) {
    return __uint_as_float((unsigned)u << 16);
}
__device__ inline unsigned short f2bf(float f) {
    unsigned x = __float_as_uint(f);
    return (unsigned short)((x + 0x7FFFu + ((x >> 16) & 1u)) >> 16);  // RNE
}
__device__ inline float lo16(unsigned u) { return __uint_as_float(u << 16); }
__device__ inline float hi16(unsigned u) { return __uint_as_float(u & 0xFFFF0000u); }

// ---- bucket build ---------------------------------------------------------

__global__ __launch_bounds__(CFBS) void count_kernel(
    const int* __restrict__ dst, int* __restrict__ cnt, int E, int NB)
{
    __shared__ int hist[NBMAX];
    int tid = threadIdx.x;
    for (int i = tid; i < NBMAX; i += CFBS) hist[i] = 0;
    __syncthreads();
    for (int e = blockIdx.x * CFBS + tid; e < E; e += NBLK * CFBS)
        atomicAdd(&hist[dst[e] >> 7], 1);
    __syncthreads();
    for (int b = tid; b < NB; b += CFBS)
        cnt[b * NBLK + blockIdx.x] = hist[b];
}

__global__ __launch_bounds__(SCBS) void scan_k1(
    const int* __restrict__ cnt, int* __restrict__ ofs,
    int* __restrict__ part, int NT)
{
    __shared__ int tmp[SCBS];
    int i = blockIdx.x * SCBS + threadIdx.x;
    int v = (i < NT) ? cnt[i] : 0;
    tmp[threadIdx.x] = v;
    __syncthreads();
    for (int off = 1; off < SCBS; off <<= 1) {
        int t = (threadIdx.x >= off) ? tmp[threadIdx.x - off] : 0;
        __syncthreads();
        tmp[threadIdx.x] += t;
        __syncthreads();
    }
    if (i < NT) ofs[i] = tmp[threadIdx.x] - v;   // exclusive within chunk
    if (threadIdx.x == SCBS - 1) part[blockIdx.x] = tmp[threadIdx.x];
}

__global__ __launch_bounds__(SCBS) void scan_k2(int* __restrict__ part, int B)
{
    __shared__ int tmp[SCBS];
    int v = (threadIdx.x < B) ? part[threadIdx.x] : 0;
    tmp[threadIdx.x] = v;
    __syncthreads();
    for (int off = 1; off < SCBS; off <<= 1) {
        int t = (threadIdx.x >= off) ? tmp[threadIdx.x - off] : 0;
        __syncthreads();
        tmp[threadIdx.x] += t;
        __syncthreads();
    }
    if (threadIdx.x < B) part[threadIdx.x] = tmp[threadIdx.x] - v;
}

__global__ __launch_bounds__(SCBS) void scan_k3(
    int* __restrict__ ofs, const int* __restrict__ part, int NT)
{
    int i = blockIdx.x * SCBS + threadIdx.x;
    if (i < NT) ofs[i] += part[blockIdx.x];
}

__global__ __launch_bounds__(CFBS) void fillp_kernel(
    const int* __restrict__ src, const int* __restrict__ dst,
    const int* __restrict__ ofs, int* __restrict__ pairs, int E, int NB)
{
    __shared__ int cur[NBMAX];
    int tid = threadIdx.x;
    for (int b = tid; b < NB; b += CFBS)
        cur[b] = ofs[b * NBLK + blockIdx.x];
    __syncthreads();
    for (int e = blockIdx.x * CFBS + tid; e < E; e += NBLK * CFBS) {
        int d = dst[e];
        int b = d >> 7, dl = d & 127;
        int pos = atomicAdd(&cur[b], 1);
        pairs[pos] = (dl << 20) | src[e];
    }
}

// per-bucket CSR finalize: writes land in bucket-local contiguous windows
__global__ __launch_bounds__(512) void bucket_csr_kernel(
    const int* __restrict__ pairs, const int* __restrict__ ofs,
    int* __restrict__ rowstart, int* __restrict__ eidx, int N, int E, int NB)
{
    __shared__ int deg[RB], pfx[RB], cur[RB];
    int tid = threadIdx.x;
    int b = blockIdx.x, n0 = b << 7;
    int e0 = ofs[b * NBLK];
    int e1 = (b + 1 < NB) ? ofs[(b + 1) * NBLK] : E;
    if (tid < RB) deg[tid] = 0;
    __syncthreads();
    for (int e = e0 + tid; e < e1; e += 512)
        atomicAdd(&deg[pairs[e] >> 20], 1);
    __syncthreads();
    if (tid < RB) pfx[tid] = deg[tid];
    __syncthreads();
    for (int off = 1; off < RB; off <<= 1) {
        int t = (tid < RB && tid >= off) ? pfx[tid - off] : 0;
        __syncthreads();
        if (tid < RB) pfx[tid] += t;
        __syncthreads();
    }
    if (tid < RB) {
        int ex = pfx[tid] - deg[tid];     // exclusive
        cur[tid] = ex;
        int n = n0 + tid;
        if (n < N) rowstart[n] = e0 + ex;
    }
    if (b == NB - 1 && tid == 0) rowstart[N] = E;
    __syncthreads();
    for (int e = e0 + tid; e < e1; e += 512) {
        int p = pairs[e];
        int pos = e0 + atomicAdd(&cur[p >> 20], 1);
        eidx[pos] = p & 0xFFFFF;
    }
}

// ---- prep: xb[N][16] bf16 (pad 9->16) AND W2/W3 -> bf16 (merged) ---------

__global__ __launch_bounds__(256) void prep_kernel(
    const float* __restrict__ x, const float* __restrict__ W2,
    const float* __restrict__ W3, unsigned short* __restrict__ xb,
    unsigned short* __restrict__ w2b, unsigned short* __restrict__ w3b, int N)
{
    int n = blockIdx.x * 256 + threadIdx.x;
    if (n < 128 * 64) {
        w2b[n] = f2bf(W2[n]);
        w3b[n] = f2bf(W3[n]);
    }
    if (n >= N) return;
    unsigned short r[16];
    #pragma unroll
    for (int k = 0; k < 9; ++k) r[k] = f2bf(x[(size_t)n * 9 + k]);
    #pragma unroll
    for (int k = 9; k < 16; ++k) r[k] = 0;
    uint4 u0, u1;
    u0.x = r[0] | ((unsigned)r[1] << 16);  u0.y = r[2] | ((unsigned)r[3] << 16);
    u0.z = r[4] | ((unsigned)r[5] << 16);  u0.w = r[6] | ((unsigned)r[7] << 16);
    u1.x = r[8] | ((unsigned)r[9] << 16);  u1.y = 0; u1.z = 0; u1.w = 0;
    *(uint4*)&xb[(size_t)n * 16]     = u0;
    *(uint4*)&xb[(size_t)n * 16 + 8] = u1;
}

// ---- layer 1: 9-dim gather + Lin 9->64 + relu, 4 nodes per wave ----------

__global__ __launch_bounds__(256) void node1v_kernel(
    const unsigned short* __restrict__ xb, const int* __restrict__ rs,
    const int* __restrict__ eidx, const float* __restrict__ W1,
    const float* __restrict__ b1, unsigned short* __restrict__ h1, int N)
{
    __shared__ float Wl[576];
    __shared__ float bl[64];
    for (int i = threadIdx.x; i < 576; i += 256) Wl[i] = W1[i];
    if (threadIdx.x < 64) bl[threadIdx.x] = b1[threadIdx.x];
    __syncthreads();
    int wid = threadIdx.x >> 6;
    int lane = threadIdx.x & 63;
    int g  = lane >> 2;     // edge group 0..15
    int d4 = lane & 3;      // dims 4*d4 .. 4*d4+3
    int nb = blockIdx.x * 16 + wid * 4;   // this wave's 4 nodes
    if (nb >= N) return;

    int n[4], e0[4], dg[4];
    float A0[4], A1[4], A2[4], A3[4];
    #pragma unroll
    for (int i = 0; i < 4; ++i) {
        n[i] = min(nb + i, N - 1);
        e0[i] = rs[n[i]];
        dg[i] = rs[n[i] + 1] - e0[i];
        A0[i] = A1[i] = A2[i] = A3[i] = 0.f;
    }
    #pragma unroll
    for (int i = 0; i < 4; ++i) {
        if (g == 0) {       // self term
            uint2 u = *(const uint2*)&xb[(size_t)n[i] * 16 + d4 * 4];
            A0[i] += lo16(u.x); A1[i] += hi16(u.x);
            A2[i] += lo16(u.y); A3[i] += hi16(u.y);
        }
    }
    int mdeg = max(max(dg[0], dg[1]), max(dg[2], dg[3]));
    for (int w0 = 0; w0 < mdeg; w0 += 64) {
        int sidx[4], wd[4];
        #pragma unroll
        for (int i = 0; i < 4; ++i) {
            wd[i] = min(max(dg[i] - w0, 0), 64);
            sidx[i] = (lane < wd[i]) ? eidx[e0[i] + w0 + lane] : 0;
        }
        int mwd = max(max(wd[0], wd[1]), max(wd[2], wd[3]));
        for (int c = 0; c < mwd; c += 16) {
            #pragma unroll
            for (int i = 0; i < 4; ++i) {
                int idx = c + g;
                int s = __shfl(sidx[i], idx < wd[i] ? idx : 0); // uniform flow
                float m = (idx < wd[i]) ? 1.f : 0.f;
                uint2 u = *(const uint2*)&xb[(size_t)s * 16 + d4 * 4];
                A0[i] += m * lo16(u.x); A1[i] += m * hi16(u.x);
                A2[i] += m * lo16(u.y); A3[i] += m * hi16(u.y);
            }
        }
    }
    #pragma unroll
    for (int m = 4; m < 64; m <<= 1) {
        #pragma unroll
        for (int i = 0; i < 4; ++i) {
            A0[i] += __shfl_xor(A0[i], m); A1[i] += __shfl_xor(A1[i], m);
            A2[i] += __shfl_xor(A2[i], m); A3[i] += __shfl_xor(A3[i], m);
        }
    }
    const float* wr = &Wl[lane * 9];
    #pragma unroll
    for (int i = 0; i < 4; ++i) {
        float xv0 = __shfl(A0[i], 0), xv1 = __shfl(A1[i], 0);
        float xv2 = __shfl(A2[i], 0), xv3 = __shfl(A3[i], 0);
        float xv4 = __shfl(A0[i], 1), xv5 = __shfl(A1[i], 1);
        float xv6 = __shfl(A2[i], 1), xv7 = __shfl(A3[i], 1);
        float xv8 = __shfl(A0[i], 2);
        float s = bl[lane] + xv0 * wr[0] + xv1 * wr[1] + xv2 * wr[2]
                + xv3 * wr[3] + xv4 * wr[4] + xv5 * wr[5] + xv6 * wr[6]
                + xv7 * wr[7] + xv8 * wr[8];
        if (nb + i < N)
            h1[(size_t)(nb + i) * 64 + lane] = f2bf(fmaxf(s, 0.f));
    }
}

// ---- 64-dim gather, 4 nodes/wave, 8 edges per inner iter (r9/r11 form) ---

template<bool BIAS_RELU>
__global__ __launch_bounds__(256) void gather64v_kernel(
    const unsigned short* __restrict__ feat, const int* __restrict__ rs,
    const int* __restrict__ eidx, const float* __restrict__ bias,
    unsigned short* __restrict__ out, int N)
{
    int wid = threadIdx.x >> 6;
    int lane = threadIdx.x & 63;
    int g  = lane >> 4;     // edge group 0..3
    int d4 = lane & 15;     // dims 4*d4 .. 4*d4+3
    int nb = blockIdx.x * 16 + wid * 4;
    if (nb >= N) return;

    int n[4], e0[4], dg[4];
    float A0[4], A1[4], A2[4], A3[4];
    #pragma unroll
    for (int i = 0; i < 4; ++i) {
        n[i] = min(nb + i, N - 1);
        e0[i] = rs[n[i]];
        dg[i] = rs[n[i] + 1] - e0[i];
        A0[i] = A1[i] = A2[i] = A3[i] = 0.f;
    }
    #pragma unroll
    for (int i = 0; i < 4; ++i) {
        if (g == 0) {       // self term
            uint2 u = *(const uint2*)&feat[(size_t)n[i] * 64 + d4 * 4];
            A0[i] += lo16(u.x); A1[i] += hi16(u.x);
            A2[i] += lo16(u.y); A3[i] += hi16(u.y);
        }
    }
    int mdeg = max(max(dg[0], dg[1]), max(dg[2], dg[3]));
    for (int w0 = 0; w0 < mdeg; w0 += 64) {
        int sidx[4], wd[4];
        #pragma unroll
        for (int i = 0; i < 4; ++i) {
            wd[i] = min(max(dg[i] - w0, 0), 64);
            sidx[i] = (lane < wd[i]) ? eidx[e0[i] + w0 + lane] : 0;
        }
        int mwd = max(max(wd[0], wd[1]), max(wd[2], wd[3]));
        for (int c = 0; c < mwd; c += 8) {
            #pragma unroll
            for (int i = 0; i < 4; ++i) {   // 8 independent loads in flight
                int i0 = c + g, i1 = c + 4 + g;
                int s0 = __shfl(sidx[i], i0 < wd[i] ? i0 : 0);  // uniform flow
                int s1 = __shfl(sidx[i], i1 < wd[i] ? i1 : 0);
                float m0 = (i0 < wd[i]) ? 1.f : 0.f;
                float m1 = (i1 < wd[i]) ? 1.f : 0.f;
                uint2 u0 = *(const uint2*)&feat[(size_t)s0 * 64 + d4 * 4];
                uint2 u1 = *(const uint2*)&feat[(size_t)s1 * 64 + d4 * 4];
                A0[i] += m0 * lo16(u0.x) + m1 * lo16(u1.x);
                A1[i] += m0 * hi16(u0.x) + m1 * hi16(u1.x);
                A2[i] += m0 * lo16(u0.y) + m1 * lo16(u1.y);
                A3[i] += m0 * hi16(u0.y) + m1 * hi16(u1.y);
            }
        }
    }
    #pragma unroll
    for (int m = 16; m < 64; m <<= 1) {
        #pragma unroll
        for (int i = 0; i < 4; ++i) {
            A0[i] += __shfl_xor(A0[i], m); A1[i] += __shfl_xor(A1[i], m);
            A2[i] += __shfl_xor(A2[i], m); A3[i] += __shfl_xor(A3[i], m);
        }
    }
    float4 bv = make_float4(0.f, 0.f, 0.f, 0.f);
    if (BIAS_RELU) bv = *(const float4*)&bias[d4 * 4];
    #pragma unroll
    for (int i = 0; i < 4; ++i) {
        if (g == 0 && nb + i < N) {
            float a0 = A0[i], a1 = A1[i], a2 = A2[i], a3 = A3[i];
            if (BIAS_RELU) {
                a0 = fmaxf(a0 + bv.x, 0.f); a1 = fmaxf(a1 + bv.y, 0.f);
                a2 = fmaxf(a2 + bv.z, 0.f); a3 = fmaxf(a3 + bv.w, 0.f);
            }
            ushort4 u;
            u.x = f2bf(a0); u.y = f2bf(a1); u.z = f2bf(a2); u.w = f2bf(a3);
            *(ushort4*)&out[(size_t)(nb + i) * 64 + d4 * 4] = u;
        }
    }
}

// ---- fused linear2+linear3: t3 = W3 . relu(W2 . a + b2) -------------------
// v3: LDS staging (fast MFMA operand reads) of PRE-CONVERTED bf16 weights
// (vectorized uint4 copies, no per-element f2bf). H2 tile wave-private ->
// single barrier after staging, none in the main path. Padded strides
// (+8 ushorts) -> 2-way bank alias only (free, m136).
//   A-frag 16x16x32: lane l -> row l&15, k-slice (l>>4)*8
//   C/D:             col = lane&15, row = (lane>>4)*4 + reg  [m89-verified]

__global__ __launch_bounds__(256) void linear23_fused_kernel(
    const unsigned short* __restrict__ A, const unsigned short* __restrict__ w2b,
    const float* __restrict__ b2, const unsigned short* __restrict__ w3b,
    unsigned short* __restrict__ t3, int N)
{
    using s8v = __attribute__((ext_vector_type(8))) short;
    using f4v = __attribute__((ext_vector_type(4))) float;
    __shared__ __align__(16) unsigned short Wb2[128 * 72];   // W2[o][k] k<64
    __shared__ __align__(16) unsigned short Wb3[64 * 136];   // W3[o][k] k<128
    __shared__ __align__(16) unsigned short H2[64 * 136];    // h2 [node][128]
    __shared__ float bl2[128];
    int tid = threadIdx.x;
    // vectorized staging: 8 ushorts per iteration per thread
    for (int i = tid; i < 1024; i += 256) {          // 1024*8 = 8192 = 128*64
        int idx = i * 8;
        int o = idx >> 6, k = idx & 63;
        *(uint4*)&Wb2[o * 72 + k] = *(const uint4*)&w2b[idx];
    }
    for (int i = tid; i < 1024; i += 256) {          // 8192 = 64*128
        int idx = i * 8;
        int o = idx >> 7, k = idx & 127;
        *(uint4*)&Wb3[o * 136 + k] = *(const uint4*)&w3b[idx];
    }
    if (tid < 128) bl2[tid] = b2[tid];
    __syncthreads();

    int w = tid >> 6, lane = tid & 63;
    int n0 = blockIdx.x * 64 + w * 16;
    int hl = lane >> 4;               // k-slice 0..3
    int ll = lane & 15;               // row (A) / col (B)

    // ---- stage 1: h2 = relu(A @ W2^T + b2) -> LDS strip ----
    int an = min(n0 + ll, N - 1);     // clamp: junk rows stay in LDS only
    const unsigned short* arow = &A[(size_t)an * 64 + hl * 8];
    s8v a1[2];
    a1[0] = *(const s8v*)&arow[0];
    a1[1] = *(const s8v*)&arow[32];

    #pragma unroll
    for (int c = 0; c < 8; ++c) {
        f4v acc = (f4v){0.f, 0.f, 0.f, 0.f};
        const unsigned short* wrow = &Wb2[(c * 16 + ll) * 72 + hl * 8];
        acc = __builtin_amdgcn_mfma_f32_16x16x32_bf16(a1[0], *(const s8v*)&wrow[0],  acc, 0, 0, 0);
        acc = __builtin_amdgcn_mfma_f32_16x16x32_bf16(a1[1], *(const s8v*)&wrow[32], acc, 0, 0, 0);
        int col = c * 16 + ll;
        float bv = bl2[col];
        #pragma unroll
        for (int r = 0; r < 4; ++r) {
            int nrow = w * 16 + hl * 4 + r;          // block-local node row
            H2[nrow * 136 + col] = f2bf(fmaxf(acc[r] + bv, 0.f));
        }
    }
    // wave-private strip: same wave wrote rows w*16..w*16+15 it now reads;
    // compiler inserts lgkmcnt waits. No cross-wave sharing -> no barrier.

    // ---- stage 2: t3 = h2 @ W3^T ----
    const unsigned short* hrow = &H2[(w * 16 + ll) * 136 + hl * 8];
    s8v a2[4];
    #pragma unroll
    for (int ks = 0; ks < 4; ++ks) a2[ks] = *(const s8v*)&hrow[ks * 32];

    #pragma unroll
    for (int c = 0; c < 4; ++c) {
        f4v acc = (f4v){0.f, 0.f, 0.f, 0.f};
        const unsigned short* wrow = &Wb3[(c * 16 + ll) * 136 + hl * 8];
        #pragma unroll
        for (int ks = 0; ks < 4; ++ks)
            acc = __builtin_amdgcn_mfma_f32_16x16x32_bf16(a2[ks], *(const s8v*)&wrow[ks * 32], acc, 0, 0, 0);
        int col = c * 16 + ll;
        #pragma unroll
        for (int r = 0; r < 4; ++r) {
            int gn = n0 + hl * 4 + r;
            if (gn < N)
                t3[(size_t)gn * 64 + col] = f2bf(acc[r]);
        }
    }
}

// ---- pool + FC ------------------------------------------------------------

__device__ inline int lower_bound_i(const int* a, int n, int v) {
    int lo = 0, hi = n;
    while (lo < hi) {
        int mid = (lo + hi) >> 1;
        if (a[mid] < v) lo = mid + 1; else hi = mid;
    }
    return lo;
}

__global__ __launch_bounds__(256) void pool_fc_kernel(
    const unsigned short* __restrict__ h3, const int* __restrict__ batch,
    const float* __restrict__ Wfc, const float* __restrict__ bfc,
    float* __restrict__ out, int N)
{
    int g = blockIdx.x;
    int tid = threadIdx.x;
    int w = tid >> 6, lane = tid & 63;
    int lo = lower_bound_i(batch, N, g);
    int hi = lower_bound_i(batch, N, g + 1);
    float sum = 0.f;
    for (int i = lo + w; i < hi; i += 4)
        sum += bf2f(h3[(size_t)i * 64 + lane]);
    __shared__ float P[4][64];
    P[w][lane] = sum;
    __syncthreads();
    if (w == 0) {
        float s = P[0][lane] + P[1][lane] + P[2][lane] + P[3][lane];
        float cnt = (float)((hi - lo) > 0 ? (hi - lo) : 1);
        P[0][lane] = s / cnt;
    }
    __syncthreads();
    if (tid < 11) {
        float s = bfc[tid];
        const float* wr = &Wfc[tid * 64];
        #pragma unroll 8
        for (int k = 0; k < 64; ++k) s += P[0][k] * wr[k];
        out[g * 11 + tid] = s;
    }
}

// ---------------------------------------------------------------------------

extern "C" void kernel_launch(void* const* d_in, const int* in_sizes, int n_in,
                              void* d_out, int out_size, void* d_ws, size_t ws_size,
                              hipStream_t stream) {
    const float* x    = (const float*)d_in[0];
    const int*   ei   = (const int*)d_in[1];
    const int*   batch= (const int*)d_in[2];
    const float* W1   = (const float*)d_in[3];
    const float* b1   = (const float*)d_in[4];
    const float* W2   = (const float*)d_in[5];
    const float* b2   = (const float*)d_in[6];
    const float* W3   = (const float*)d_in[7];
    const float* b3   = (const float*)d_in[8];
    const float* Wfc  = (const float*)d_in[9];
    const float* bfc  = (const float*)d_in[10];
    float* out = (float*)d_out;

    const int N = in_sizes[2];
    const int E = in_sizes[1] / 2;
    const int G = out_size / 11;
    const int* src = ei;
    const int* dst = ei + E;
    const int NB = (N + RB - 1) / RB;      // buckets
    const int NT = NB * NBLK;              // count entries
    const int SB = (NT + SCBS - 1) / SCBS; // scan chunks

    // workspace (bf16 tables):
    //   B1 64N (h1 -> t3) | B2 64N (buf2 -> h3) | XB 16N (xb)
    //   ints: pairs E | eidx E | rowstart N+1 | cnt NT | ofs NT | part SCBS
    //   then w2b/w3b (bf16 weights, 16B-aligned)
    unsigned short* B1 = (unsigned short*)d_ws;
    unsigned short* B2 = B1 + (size_t)64 * N;
    unsigned short* XB = B2 + (size_t)64 * N;
    int* pairs    = (int*)(XB + (size_t)16 * N);
    int* eidx     = pairs + E;
    int* rowstart = eidx + E;
    int* cnt      = rowstart + (N + 1);
    int* ofs      = cnt + NT;
    int* part     = ofs + NT;
    unsigned short* w2b =
        (unsigned short*)(((uintptr_t)(part + SCBS) + 15) & ~(uintptr_t)15);
    unsigned short* w3b = w2b + 128 * 64;

    unsigned short* h1   = B1;
    unsigned short* buf2 = B2;
    unsigned short* t3   = B1;   // h1 dead after gather2
    unsigned short* h3   = B2;   // buf2 dead after fused linear
    unsigned short* xb   = XB;

    // ---- build: bucket-grouped pairs, then per-bucket CSR ----
    count_kernel<<<NBLK, CFBS, 0, stream>>>(dst, cnt, E, NB);
    scan_k1<<<SB, SCBS, 0, stream>>>(cnt, ofs, part, NT);
    scan_k2<<<1, SCBS, 0, stream>>>(part, SB);
    scan_k3<<<SB, SCBS, 0, stream>>>(ofs, part, NT);
    fillp_kernel<<<NBLK, CFBS, 0, stream>>>(src, dst, ofs, pairs, E, NB);
    bucket_csr_kernel<<<NB, 512, 0, stream>>>(pairs, ofs, rowstart, eidx, N, E, NB);
    prep_kernel<<<(N + 255) / 256, 256, 0, stream>>>(x, W2, W3, xb, w2b, w3b, N);

    // ---- layer 1: vectorized 9-dim gather + Lin 9->64 + relu ----
    node1v_kernel<<<(N + 15) / 16, 256, 0, stream>>>(
        xb, rowstart, eidx, W1, b1, h1, N);

    // ---- layer 2 gather, then fused Lin2+Lin3 (h2 never leaves LDS) ----
    gather64v_kernel<false><<<(N + 15) / 16, 256, 0, stream>>>(
        h1, rowstart, eidx, nullptr, buf2, N);
    linear23_fused_kernel<<<(N + 63) / 64, 256, 0, stream>>>(
        buf2, w2b, b2, w3b, t3, N);

    // ---- layer 3 gather (+b3, relu) ----
    gather64v_kernel<true><<<(N + 15) / 16, 256, 0, stream>>>(
        t3, rowstart, eidx, b3, h3, N);

    // ---- pool + FC ----
    pool_fc_kernel<<<G, 256, 0, stream>>>(h3, batch, Wfc, bfc, out, N);
}

// Round 15
// 202.597 us; speedup vs baseline: 1.1064x; 1.0042x over previous
//
#include <hip/hip_runtime.h>
#include <hip/hip_bf16.h>

// ---------------------------------------------------------------------------
// GIN (3 layers, eps=0) + global mean pool + FC.
//
// Lessons: r1 global f32 atomics = 64B write-through; r2 per-node CSR fill =
//   105MB dirty lines; r3 block-per-bucket agg = latency collapse; r5 linears
//   LDS-read-bound -> r6 MFMA linears; r7 __shfl in divergent flow = garbage;
//   r8 1 node/wave = serial-chain bound; r9 4 nodes/wave + 8 loads in flight
//   = gather sweet spot (43us, VGPR 48); r10 global atomics on hot bins =
//   RMW serialization; r11 degree-balancing = zero gain; r12 16-deep unroll
//   = VGPR/occ regression; r13 B-frags-from-global = serial L1 loads; r14
//   LDS-staged preconverted weights = fixed (203us).
// Gather floor analysis (r9-r14): 43.0 +/- 0.2us invariant across order/
//   balance/unroll variants. Compulsory traffic: every XCD pulls the whole
//   12.8MB table through its private L2 (random sources) = 8x12.8 ~ 102MB;
//   measured FETCH 82MB (87% line coverage) at ~2.2TB/s = the L3 random-
//   128B-line service rate. fp8 rejected on error budget (absmax 0.25 ->
//   ~1.5+ vs threshold 1.15); src-quartering/dim-splitting rejected (same
//   compulsory bound).
// r15: launch-count trims only: prep fused into count; scan_k2 deleted
//   (scan_k3 blocks redundantly self-scan the 196-entry partials). 12->10
//   launches; compute kernels untouched.
// ---------------------------------------------------------------------------

#define NBLK 256      // blocks for edge count/fill
#define CFBS 512      // threads for edge count/fill
#define RB   128      // nodes per bucket
#define NBMAX 1024    // max buckets (N <= 131072)
#define SCBS 1024     // scan chunk

__device__ inline float bf2f(unsigned short u) {
    return __uint_as_float((unsigned)u << 16);
}
__device__ inline unsigned short f2bf(float f) {
    unsigned x = __float_as_uint(f);
    return (unsigned short)((x + 0x7FFFu + ((x >> 16) & 1u)) >> 16);  // RNE
}
__device__ inline float lo16(unsigned u) { return __uint_as_float(u << 16); }
__device__ inline float hi16(unsigned u) { return __uint_as_float(u & 0xFFFF0000u); }

// ---- build: count (+fused prep) ------------------------------------------

__global__ __launch_bounds__(CFBS) void count_prep_kernel(
    const int* __restrict__ dst, int* __restrict__ cnt,
    const float* __restrict__ x, const float* __restrict__ W2,
    const float* __restrict__ W3, unsigned short* __restrict__ xb,
    unsigned short* __restrict__ w2b, unsigned short* __restrict__ w3b,
    int E, int NB, int N)
{
    __shared__ int hist[NBMAX];
    int tid = threadIdx.x;
    for (int i = tid; i < NBMAX; i += CFBS) hist[i] = 0;
    __syncthreads();
    for (int e = blockIdx.x * CFBS + tid; e < E; e += NBLK * CFBS)
        atomicAdd(&hist[dst[e] >> 7], 1);
    __syncthreads();
    for (int b = tid; b < NB; b += CFBS)
        cnt[b * NBLK + blockIdx.x] = hist[b];

    // fused prep (independent streaming work, hides under random dst reads)
    int gtid = blockIdx.x * CFBS + tid;
    int gstr = NBLK * CFBS;
    for (int i = gtid; i < 128 * 64; i += gstr) {
        w2b[i] = f2bf(W2[i]);
        w3b[i] = f2bf(W3[i]);
    }
    for (int n = gtid; n < N; n += gstr) {
        unsigned short r[16];
        #pragma unroll
        for (int k = 0; k < 9; ++k) r[k] = f2bf(x[(size_t)n * 9 + k]);
        #pragma unroll
        for (int k = 9; k < 16; ++k) r[k] = 0;
        uint4 u0, u1;
        u0.x = r[0] | ((unsigned)r[1] << 16);  u0.y = r[2] | ((unsigned)r[3] << 16);
        u0.z = r[4] | ((unsigned)r[5] << 16);  u0.w = r[6] | ((unsigned)r[7] << 16);
        u1.x = r[8] | ((unsigned)r[9] << 16);  u1.y = 0; u1.z = 0; u1.w = 0;
        *(uint4*)&xb[(size_t)n * 16]     = u0;
        *(uint4*)&xb[(size_t)n * 16 + 8] = u1;
    }
}

__global__ __launch_bounds__(SCBS) void scan_k1(
    const int* __restrict__ cnt, int* __restrict__ ofs,
    int* __restrict__ part, int NT)
{
    __shared__ int tmp[SCBS];
    int i = blockIdx.x * SCBS + threadIdx.x;
    int v = (i < NT) ? cnt[i] : 0;
    tmp[threadIdx.x] = v;
    __syncthreads();
    for (int off = 1; off < SCBS; off <<= 1) {
        int t = (threadIdx.x >= off) ? tmp[threadIdx.x - off] : 0;
        __syncthreads();
        tmp[threadIdx.x] += t;
        __syncthreads();
    }
    if (i < NT) ofs[i] = tmp[threadIdx.x] - v;   // exclusive within chunk
    if (threadIdx.x == SCBS - 1) part[blockIdx.x] = tmp[threadIdx.x];
}

// add-back with redundant per-block scan of the partials (replaces scan_k2)
__global__ __launch_bounds__(SCBS) void scan_k3(
    int* __restrict__ ofs, const int* __restrict__ part, int NT, int SB)
{
    __shared__ int tmp[SCBS];
    int t = threadIdx.x;
    tmp[t] = (t < SB) ? part[t] : 0;
    __syncthreads();
    for (int off = 1; off < SCBS; off <<= 1) {
        int v = (t >= off) ? tmp[t - off] : 0;
        __syncthreads();
        tmp[t] += v;
        __syncthreads();
    }
    int add = (blockIdx.x > 0) ? tmp[blockIdx.x - 1] : 0;   // exclusive offset
    int i = blockIdx.x * SCBS + t;
    if (i < NT) ofs[i] += add;
}

__global__ __launch_bounds__(CFBS) void fillp_kernel(
    const int* __restrict__ src, const int* __restrict__ dst,
    const int* __restrict__ ofs, int* __restrict__ pairs, int E, int NB)
{
    __shared__ int cur[NBMAX];
    int tid = threadIdx.x;
    for (int b = tid; b < NB; b += CFBS)
        cur[b] = ofs[b * NBLK + blockIdx.x];
    __syncthreads();
    for (int e = blockIdx.x * CFBS + tid; e < E; e += NBLK * CFBS) {
        int d = dst[e];
        int b = d >> 7, dl = d & 127;
        int pos = atomicAdd(&cur[b], 1);
        pairs[pos] = (dl << 20) | src[e];
    }
}

// per-bucket CSR finalize: writes land in bucket-local contiguous windows
__global__ __launch_bounds__(512) void bucket_csr_kernel(
    const int* __restrict__ pairs, const int* __restrict__ ofs,
    int* __restrict__ rowstart, int* __restrict__ eidx, int N, int E, int NB)
{
    __shared__ int deg[RB], pfx[RB], cur[RB];
    int tid = threadIdx.x;
    int b = blockIdx.x, n0 = b << 7;
    int e0 = ofs[b * NBLK];
    int e1 = (b + 1 < NB) ? ofs[(b + 1) * NBLK] : E;
    if (tid < RB) deg[tid] = 0;
    __syncthreads();
    for (int e = e0 + tid; e < e1; e += 512)
        atomicAdd(&deg[pairs[e] >> 20], 1);
    __syncthreads();
    if (tid < RB) pfx[tid] = deg[tid];
    __syncthreads();
    for (int off = 1; off < RB; off <<= 1) {
        int t = (tid < RB && tid >= off) ? pfx[tid - off] : 0;
        __syncthreads();
        if (tid < RB) pfx[tid] += t;
        __syncthreads();
    }
    if (tid < RB) {
        int ex = pfx[tid] - deg[tid];     // exclusive
        cur[tid] = ex;
        int n = n0 + tid;
        if (n < N) rowstart[n] = e0 + ex;
    }
    if (b == NB - 1 && tid == 0) rowstart[N] = E;
    __syncthreads();
    for (int e = e0 + tid; e < e1; e += 512) {
        int p = pairs[e];
        int pos = e0 + atomicAdd(&cur[p >> 20], 1);
        eidx[pos] = p & 0xFFFFF;
    }
}

// ---- layer 1: 9-dim gather + Lin 9->64 + relu, 4 nodes per wave ----------

__global__ __launch_bounds__(256) void node1v_kernel(
    const unsigned short* __restrict__ xb, const int* __restrict__ rs,
    const int* __restrict__ eidx, const float* __restrict__ W1,
    const float* __restrict__ b1, unsigned short* __restrict__ h1, int N)
{
    __shared__ float Wl[576];
    __shared__ float bl[64];
    for (int i = threadIdx.x; i < 576; i += 256) Wl[i] = W1[i];
    if (threadIdx.x < 64) bl[threadIdx.x] = b1[threadIdx.x];
    __syncthreads();
    int wid = threadIdx.x >> 6;
    int lane = threadIdx.x & 63;
    int g  = lane >> 2;     // edge group 0..15
    int d4 = lane & 3;      // dims 4*d4 .. 4*d4+3
    int nb = blockIdx.x * 16 + wid * 4;   // this wave's 4 nodes
    if (nb >= N) return;

    int n[4], e0[4], dg[4];
    float A0[4], A1[4], A2[4], A3[4];
    #pragma unroll
    for (int i = 0; i < 4; ++i) {
        n[i] = min(nb + i, N - 1);
        e0[i] = rs[n[i]];
        dg[i] = rs[n[i] + 1] - e0[i];
        A0[i] = A1[i] = A2[i] = A3[i] = 0.f;
    }
    #pragma unroll
    for (int i = 0; i < 4; ++i) {
        if (g == 0) {       // self term
            uint2 u = *(const uint2*)&xb[(size_t)n[i] * 16 + d4 * 4];
            A0[i] += lo16(u.x); A1[i] += hi16(u.x);
            A2[i] += lo16(u.y); A3[i] += hi16(u.y);
        }
    }
    int mdeg = max(max(dg[0], dg[1]), max(dg[2], dg[3]));
    for (int w0 = 0; w0 < mdeg; w0 += 64) {
        int sidx[4], wd[4];
        #pragma unroll
        for (int i = 0; i < 4; ++i) {
            wd[i] = min(max(dg[i] - w0, 0), 64);
            sidx[i] = (lane < wd[i]) ? eidx[e0[i] + w0 + lane] : 0;
        }
        int mwd = max(max(wd[0], wd[1]), max(wd[2], wd[3]));
        for (int c = 0; c < mwd; c += 16) {
            #pragma unroll
            for (int i = 0; i < 4; ++i) {
                int idx = c + g;
                int s = __shfl(sidx[i], idx < wd[i] ? idx : 0); // uniform flow
                float m = (idx < wd[i]) ? 1.f : 0.f;
                uint2 u = *(const uint2*)&xb[(size_t)s * 16 + d4 * 4];
                A0[i] += m * lo16(u.x); A1[i] += m * hi16(u.x);
                A2[i] += m * lo16(u.y); A3[i] += m * hi16(u.y);
            }
        }
    }
    #pragma unroll
    for (int m = 4; m < 64; m <<= 1) {
        #pragma unroll
        for (int i = 0; i < 4; ++i) {
            A0[i] += __shfl_xor(A0[i], m); A1[i] += __shfl_xor(A1[i], m);
            A2[i] += __shfl_xor(A2[i], m); A3[i] += __shfl_xor(A3[i], m);
        }
    }
    const float* wr = &Wl[lane * 9];
    #pragma unroll
    for (int i = 0; i < 4; ++i) {
        float xv0 = __shfl(A0[i], 0), xv1 = __shfl(A1[i], 0);
        float xv2 = __shfl(A2[i], 0), xv3 = __shfl(A3[i], 0);
        float xv4 = __shfl(A0[i], 1), xv5 = __shfl(A1[i], 1);
        float xv6 = __shfl(A2[i], 1), xv7 = __shfl(A3[i], 1);
        float xv8 = __shfl(A0[i], 2);
        float s = bl[lane] + xv0 * wr[0] + xv1 * wr[1] + xv2 * wr[2]
                + xv3 * wr[3] + xv4 * wr[4] + xv5 * wr[5] + xv6 * wr[6]
                + xv7 * wr[7] + xv8 * wr[8];
        if (nb + i < N)
            h1[(size_t)(nb + i) * 64 + lane] = f2bf(fmaxf(s, 0.f));
    }
}

// ---- 64-dim gather, 4 nodes/wave, 8 edges per inner iter (r9 form) -------

template<bool BIAS_RELU>
__global__ __launch_bounds__(256) void gather64v_kernel(
    const unsigned short* __restrict__ feat, const int* __restrict__ rs,
    const int* __restrict__ eidx, const float* __restrict__ bias,
    unsigned short* __restrict__ out, int N)
{
    int wid = threadIdx.x >> 6;
    int lane = threadIdx.x & 63;
    int g  = lane >> 4;     // edge group 0..3
    int d4 = lane & 15;     // dims 4*d4 .. 4*d4+3
    int nb = blockIdx.x * 16 + wid * 4;
    if (nb >= N) return;

    int n[4], e0[4], dg[4];
    float A0[4], A1[4], A2[4], A3[4];
    #pragma unroll
    for (int i = 0; i < 4; ++i) {
        n[i] = min(nb + i, N - 1);
        e0[i] = rs[n[i]];
        dg[i] = rs[n[i] + 1] - e0[i];
        A0[i] = A1[i] = A2[i] = A3[i] = 0.f;
    }
    #pragma unroll
    for (int i = 0; i < 4; ++i) {
        if (g == 0) {       // self term
            uint2 u = *(const uint2*)&feat[(size_t)n[i] * 64 + d4 * 4];
            A0[i] += lo16(u.x); A1[i] += hi16(u.x);
            A2[i] += lo16(u.y); A3[i] += hi16(u.y);
        }
    }
    int mdeg = max(max(dg[0], dg[1]), max(dg[2], dg[3]));
    for (int w0 = 0; w0 < mdeg; w0 += 64) {
        int sidx[4], wd[4];
        #pragma unroll
        for (int i = 0; i < 4; ++i) {
            wd[i] = min(max(dg[i] - w0, 0), 64);
            sidx[i] = (lane < wd[i]) ? eidx[e0[i] + w0 + lane] : 0;
        }
        int mwd = max(max(wd[0], wd[1]), max(wd[2], wd[3]));
        for (int c = 0; c < mwd; c += 8) {
            #pragma unroll
            for (int i = 0; i < 4; ++i) {   // 8 independent loads in flight
                int i0 = c + g, i1 = c + 4 + g;
                int s0 = __shfl(sidx[i], i0 < wd[i] ? i0 : 0);  // uniform flow
                int s1 = __shfl(sidx[i], i1 < wd[i] ? i1 : 0);
                float m0 = (i0 < wd[i]) ? 1.f : 0.f;
                float m1 = (i1 < wd[i]) ? 1.f : 0.f;
                uint2 u0 = *(const uint2*)&feat[(size_t)s0 * 64 + d4 * 4];
                uint2 u1 = *(const uint2*)&feat[(size_t)s1 * 64 + d4 * 4];
                A0[i] += m0 * lo16(u0.x) + m1 * lo16(u1.x);
                A1[i] += m0 * hi16(u0.x) + m1 * hi16(u1.x);
                A2[i] += m0 * lo16(u0.y) + m1 * lo16(u1.y);
                A3[i] += m0 * hi16(u0.y) + m1 * hi16(u1.y);
            }
        }
    }
    #pragma unroll
    for (int m = 16; m < 64; m <<= 1) {
        #pragma unroll
        for (int i = 0; i < 4; ++i) {
            A0[i] += __shfl_xor(A0[i], m); A1[i] += __shfl_xor(A1[i], m);
            A2[i] += __shfl_xor(A2[i], m); A3[i] += __shfl_xor(A3[i], m);
        }
    }
    float4 bv = make_float4(0.f, 0.f, 0.f, 0.f);
    if (BIAS_RELU) bv = *(const float4*)&bias[d4 * 4];
    #pragma unroll
    for (int i = 0; i < 4; ++i) {
        if (g == 0 && nb + i < N) {
            float a0 = A0[i], a1 = A1[i], a2 = A2[i], a3 = A3[i];
            if (BIAS_RELU) {
                a0 = fmaxf(a0 + bv.x, 0.f); a1 = fmaxf(a1 + bv.y, 0.f);
                a2 = fmaxf(a2 + bv.z, 0.f); a3 = fmaxf(a3 + bv.w, 0.f);
            }
            ushort4 u;
            u.x = f2bf(a0); u.y = f2bf(a1); u.z = f2bf(a2); u.w = f2bf(a3);
            *(ushort4*)&out[(size_t)(nb + i) * 64 + d4 * 4] = u;
        }
    }
}

// ---- fused linear2+linear3: t3 = W3 . relu(W2 . a + b2) (r14 v3) ----------

__global__ __launch_bounds__(256) void linear23_fused_kernel(
    const unsigned short* __restrict__ A, const unsigned short* __restrict__ w2b,
    const float* __restrict__ b2, const unsigned short* __restrict__ w3b,
    unsigned short* __restrict__ t3, int N)
{
    using s8v = __attribute__((ext_vector_type(8))) short;
    using f4v = __attribute__((ext_vector_type(4))) float;
    __shared__ __align__(16) unsigned short Wb2[128 * 72];   // W2[o][k] k<64
    __shared__ __align__(16) unsigned short Wb3[64 * 136];   // W3[o][k] k<128
    __shared__ __align__(16) unsigned short H2[64 * 136];    // h2 [node][128]
    __shared__ float bl2[128];
    int tid = threadIdx.x;
    for (int i = tid; i < 1024; i += 256) {          // 1024*8 = 8192 = 128*64
        int idx = i * 8;
        int o = idx >> 6, k = idx & 63;
        *(uint4*)&Wb2[o * 72 + k] = *(const uint4*)&w2b[idx];
    }
    for (int i = tid; i < 1024; i += 256) {          // 8192 = 64*128
        int idx = i * 8;
        int o = idx >> 7, k = idx & 127;
        *(uint4*)&Wb3[o * 136 + k] = *(const uint4*)&w3b[idx];
    }
    if (tid < 128) bl2[tid] = b2[tid];
    __syncthreads();

    int w = tid >> 6, lane = tid & 63;
    int n0 = blockIdx.x * 64 + w * 16;
    int hl = lane >> 4;               // k-slice 0..3
    int ll = lane & 15;               // row (A) / col (B)

    // ---- stage 1: h2 = relu(A @ W2^T + b2) -> LDS strip ----
    int an = min(n0 + ll, N - 1);     // clamp: junk rows stay in LDS only
    const unsigned short* arow = &A[(size_t)an * 64 + hl * 8];
    s8v a1[2];
    a1[0] = *(const s8v*)&arow[0];
    a1[1] = *(const s8v*)&arow[32];

    #pragma unroll
    for (int c = 0; c < 8; ++c) {
        f4v acc = (f4v){0.f, 0.f, 0.f, 0.f};
        const unsigned short* wrow = &Wb2[(c * 16 + ll) * 72 + hl * 8];
        acc = __builtin_amdgcn_mfma_f32_16x16x32_bf16(a1[0], *(const s8v*)&wrow[0],  acc, 0, 0, 0);
        acc = __builtin_amdgcn_mfma_f32_16x16x32_bf16(a1[1], *(const s8v*)&wrow[32], acc, 0, 0, 0);
        int col = c * 16 + ll;
        float bv = bl2[col];
        #pragma unroll
        for (int r = 0; r < 4; ++r) {
            int nrow = w * 16 + hl * 4 + r;          // block-local node row
            H2[nrow * 136 + col] = f2bf(fmaxf(acc[r] + bv, 0.f));
        }
    }
    // wave-private strip: same wave wrote rows w*16..w*16+15 it now reads;
    // compiler inserts lgkmcnt waits. No cross-wave sharing -> no barrier.

    // ---- stage 2: t3 = h2 @ W3^T ----
    const unsigned short* hrow = &H2[(w * 16 + ll) * 136 + hl * 8];
    s8v a2[4];
    #pragma unroll
    for (int ks = 0; ks < 4; ++ks) a2[ks] = *(const s8v*)&hrow[ks * 32];

    #pragma unroll
    for (int c = 0; c < 4; ++c) {
        f4v acc = (f4v){0.f, 0.f, 0.f, 0.f};
        const unsigned short* wrow = &Wb3[(c * 16 + ll) * 136 + hl * 8];
        #pragma unroll
        for (int ks = 0; ks < 4; ++ks)
            acc = __builtin_amdgcn_mfma_f32_16x16x32_bf16(a2[ks], *(const s8v*)&wrow[ks * 32], acc, 0, 0, 0);
        int col = c * 16 + ll;
        #pragma unroll
        for (int r = 0; r < 4; ++r) {
            int gn = n0 + hl * 4 + r;
            if (gn < N)
                t3[(size_t)gn * 64 + col] = f2bf(acc[r]);
        }
    }
}

// ---- pool + FC ------------------------------------------------------------

__device__ inline int lower_bound_i(const int* a, int n, int v) {
    int lo = 0, hi = n;
    while (lo < hi) {
        int mid = (lo + hi) >> 1;
        if (a[mid] < v) lo = mid + 1; else hi = mid;
    }
    return lo;
}

__global__ __launch_bounds__(256) void pool_fc_kernel(
    const unsigned short* __restrict__ h3, const int* __restrict__ batch,
    const float* __restrict__ Wfc, const float* __restrict__ bfc,
    float* __restrict__ out, int N)
{
    int g = blockIdx.x;
    int tid = threadIdx.x;
    int w = tid >> 6, lane = tid & 63;
    int lo = lower_bound_i(batch, N, g);
    int hi = lower_bound_i(batch, N, g + 1);
    float sum = 0.f;
    for (int i = lo + w; i < hi; i += 4)
        sum += bf2f(h3[(size_t)i * 64 + lane]);
    __shared__ float P[4][64];
    P[w][lane] = sum;
    __syncthreads();
    if (w == 0) {
        float s = P[0][lane] + P[1][lane] + P[2][lane] + P[3][lane];
        float cnt = (float)((hi - lo) > 0 ? (hi - lo) : 1);
        P[0][lane] = s / cnt;
    }
    __syncthreads();
    if (tid < 11) {
        float s = bfc[tid];
        const float* wr = &Wfc[tid * 64];
        #pragma unroll 8
        for (int k = 0; k < 64; ++k) s += P[0][k] * wr[k];
        out[g * 11 + tid] = s;
    }
}

// ---------------------------------------------------------------------------

extern "C" void kernel_launch(void* const* d_in, const int* in_sizes, int n_in,
                              void* d_out, int out_size, void* d_ws, size_t ws_size,
                              hipStream_t stream) {
    const float* x    = (const float*)d_in[0];
    const int*   ei   = (const int*)d_in[1];
    const int*   batch= (const int*)d_in[2];
    const float* W1   = (const float*)d_in[3];
    const float* b1   = (const float*)d_in[4];
    const float* W2   = (const float*)d_in[5];
    const float* b2   = (const float*)d_in[6];
    const float* W3   = (const float*)d_in[7];
    const float* b3   = (const float*)d_in[8];
    const float* Wfc  = (const float*)d_in[9];
    const float* bfc  = (const float*)d_in[10];
    float* out = (float*)d_out;

    const int N = in_sizes[2];
    const int E = in_sizes[1] / 2;
    const int G = out_size / 11;
    const int* src = ei;
    const int* dst = ei + E;
    const int NB = (N + RB - 1) / RB;      // buckets
    const int NT = NB * NBLK;              // count entries
    const int SB = (NT + SCBS - 1) / SCBS; // scan chunks (<= SCBS)

    // workspace (bf16 tables):
    //   B1 64N (h1 -> t3) | B2 64N (buf2 -> h3) | XB 16N (xb)
    //   ints: pairs E | eidx E | rowstart N+1 | cnt NT | ofs NT | part SCBS
    //   then w2b/w3b (bf16 weights, 16B-aligned)
    unsigned short* B1 = (unsigned short*)d_ws;
    unsigned short* B2 = B1 + (size_t)64 * N;
    unsigned short* XB = B2 + (size_t)64 * N;
    int* pairs    = (int*)(XB + (size_t)16 * N);
    int* eidx     = pairs + E;
    int* rowstart = eidx + E;
    int* cnt      = rowstart + (N + 1);
    int* ofs      = cnt + NT;
    int* part     = ofs + NT;
    unsigned short* w2b =
        (unsigned short*)(((uintptr_t)(part + SCBS) + 15) & ~(uintptr_t)15);
    unsigned short* w3b = w2b + 128 * 64;

    unsigned short* h1   = B1;
    unsigned short* buf2 = B2;
    unsigned short* t3   = B1;   // h1 dead after gather2
    unsigned short* h3   = B2;   // buf2 dead after fused linear
    unsigned short* xb   = XB;

    // ---- build (+fused prep): bucket pairs, then per-bucket CSR ----
    count_prep_kernel<<<NBLK, CFBS, 0, stream>>>(
        dst, cnt, x, W2, W3, xb, w2b, w3b, E, NB, N);
    scan_k1<<<SB, SCBS, 0, stream>>>(cnt, ofs, part, NT);
    scan_k3<<<SB, SCBS, 0, stream>>>(ofs, part, NT, SB);
    fillp_kernel<<<NBLK, CFBS, 0, stream>>>(src, dst, ofs, pairs, E, NB);
    bucket_csr_kernel<<<NB, 512, 0, stream>>>(pairs, ofs, rowstart, eidx, N, E, NB);

    // ---- layer 1: vectorized 9-dim gather + Lin 9->64 + relu ----
    node1v_kernel<<<(N + 15) / 16, 256, 0, stream>>>(
        xb, rowstart, eidx, W1, b1, h1, N);

    // ---- layer 2 gather, then fused Lin2+Lin3 (h2 never leaves LDS) ----
    gather64v_kernel<false><<<(N + 15) / 16, 256, 0, stream>>>(
        h1, rowstart, eidx, nullptr, buf2, N);
    linear23_fused_kernel<<<(N + 63) / 64, 256, 0, stream>>>(
        buf2, w2b, b2, w3b, t3, N);

    // ---- layer 3 gather (+b3, relu) ----
    gather64v_kernel<true><<<(N + 15) / 16, 256, 0, stream>>>(
        t3, rowstart, eidx, b3, h3, N);

    // ---- pool + FC ----
    pool_fc_kernel<<<G, 256, 0, stream>>>(h3, batch, Wfc, bfc, out, N);
}